// Round 10
// baseline (272.744 us; speedup 1.0000x reference)
//
#include <hip/hip_runtime.h>
#include <math.h>

#define D_DIM 512

typedef short short8v __attribute__((ext_vector_type(8)));
typedef unsigned short ushort8v __attribute__((ext_vector_type(8)));
typedef unsigned short ushort4v __attribute__((ext_vector_type(4)));
typedef float f32x16 __attribute__((ext_vector_type(16)));

__device__ inline unsigned short f2bf(float f) {
    union { float f; unsigned int u; } a; a.f = f;
    unsigned int u = a.u;
    unsigned int r = (u + 0x7fffu + ((u >> 16) & 1u)) >> 16;  // RNE
    return (unsigned short)r;
}

// fast tanh: 1 - 2/(e^{2y}+1); saturates correctly at +-1
__device__ inline float fast_tanh(float y) {
    float e2 = __expf(2.f * y);
    return 1.f - __fdividef(2.f, e2 + 1.f);
}

// 32-bit LDS offset for inline-asm DS ops
__device__ inline unsigned ldsaddr(const void* p) {
    return (unsigned)(size_t)(__attribute__((address_space(3))) const void*)p;
}

// async 16B global -> LDS (HW scatters lane i at wave-uniform base + i*16)
#define ASYNC_CP16(gp, lp) \
    __builtin_amdgcn_global_load_lds( \
        (const __attribute__((address_space(1))) void*)(gp), \
        (__attribute__((address_space(3))) void*)(lp), 16, 0, 0)

// ---------------------------------------------------------------------------
// A-tile fragment layout (R5-verified):
// element x[row][k] -> idx (((ks*2+mi)*2+hf)*32 + r5)*8 + j  (ushorts),
//   ks=k>>4, hf=(k>>3)&1, j=k&7, mi=row>>5, r5=row&31.
// ---------------------------------------------------------------------------
__device__ __forceinline__ void pack_store(unsigned short* dst, int row, int c4, float4 v) {
    int ks = c4 >> 4, hf = (c4 >> 3) & 1, j0 = c4 & 7;
    int mi = row >> 5, r5 = row & 31;
    ushort4v pk;
    pk[0] = f2bf(v.x); pk[1] = f2bf(v.y); pk[2] = f2bf(v.z); pk[3] = f2bf(v.w);
    *(ushort4v*)&dst[(((ks * 2 + mi) * 2 + hf) * 32 + r5) * 8 + j0] = pk;
}

// ---------------------------------------------------------------------------
// wt body: W[k][e] fp32 -> Wb2 bf16, tiled in 32 stages of 16 k
// (B-fragment order).  Wb2 ushort idx: s16*8192 + ((g*2+half)*32+nl)*8 + j
//   holding W[k = s16*16 + half*8 + j][e = g*32 + nl].
// ---------------------------------------------------------------------------
__device__ __forceinline__ void wt_body(const float* __restrict__ W,
                                        unsigned short* __restrict__ Wb2,
                                        unsigned short* lbuf, int s, int tid) {
    #pragma unroll
    for (int i = 0; i < 4; ++i) {
        int flat = tid + i * 1024;     // 0..4095 float4-chunks of this stage-pair
        int kr = flat >> 7;            // 0..31
        int e4 = (flat & 127) * 4;
        float4 v = *(const float4*)(W + (size_t)(s * 32 + kr) * D_DIM + e4);
        int ks = kr >> 4, half = (kr >> 3) & 1, j = kr & 7;
        float vv[4] = {v.x, v.y, v.z, v.w};
        #pragma unroll
        for (int q = 0; q < 4; ++q) {
            int e = e4 + q, g = e >> 5, nl = e & 31;
            lbuf[ks * 8192 + ((g * 2 + half) * 32 + nl) * 8 + j] = f2bf(vv[q]);
        }
    }
    __syncthreads();
    #pragma unroll
    for (int i = 0; i < 2; ++i) {
        int c = tid + i * 1024;        // 0..2047 8-ushort chunks
        *(ushort8v*)(Wb2 + (size_t)s * 16384 + c * 8) = *(const ushort8v*)&lbuf[c * 8];
    }
}

// ---------------------------------------------------------------------------
// wt_kernel: standalone (mid-tier path).  Verbatim behavior since round 5.
// ---------------------------------------------------------------------------
__global__ __launch_bounds__(1024) void wt_kernel(const float* __restrict__ W,
                                                  unsigned short* __restrict__ Wb2,
                                                  float* __restrict__ zero_base,
                                                  int zero_count) {
    __shared__ __align__(16) unsigned short lbuf[16384];
    const int s = blockIdx.x;
    const int tid = threadIdx.x;
    if (s == 0) {
        for (int i = tid; i < zero_count; i += 1024) zero_base[i] = 0.f;
    }
    wt_body(W, Wb2, lbuf, s, tid);
}

// ---------------------------------------------------------------------------
// prep_kernel (big path): blocks 0..15 = wt stages (block 0 zeroes numer/
// denom); blocks 16.. = x fp32 -> Xb bf16, one 64-row tile per block, in the
// EXACT gemm A-fragment order so the gemm can DMA it linearly.
// Pattern = wt: coalesced read -> f2bf -> LDS scatter (fragment order) ->
// barrier -> linear coalesced global write.  Pure BW (~201 MB total).
// ---------------------------------------------------------------------------
__global__ __launch_bounds__(1024) void prep_kernel(
    const float* __restrict__ W, unsigned short* __restrict__ Wb2,
    const float* __restrict__ x, unsigned short* __restrict__ Xb,
    float* __restrict__ zero_base, int zero_count)
{
    __shared__ __align__(16) unsigned short lbuf[32768];   // 64 KiB
    const int tid = threadIdx.x;
    if (blockIdx.x < 16) {
        const int s = blockIdx.x;
        if (s == 0) {
            for (int i = tid; i < zero_count; i += 1024) zero_base[i] = 0.f;
        }
        wt_body(W, Wb2, lbuf, s, tid);
        return;
    }
    const int tile = blockIdx.x - 16;                     // 0..M/64-1
    const float* x0 = x + (size_t)tile * 64 * D_DIM;
    unsigned short* xb0 = Xb + (size_t)tile * 32768;
    #pragma unroll
    for (int i = 0; i < 8; ++i) {
        int chunk = tid + i * 1024;        // 0..8191 float4-chunks
        int row = chunk >> 7;              // 0..63
        int c4  = (chunk & 127) * 4;       // coalesced across tid
        float4 v = *(const float4*)(x0 + (size_t)row * D_DIM + c4);
        pack_store(lbuf, row, c4, v);
    }
    __syncthreads();
    #pragma unroll
    for (int i = 0; i < 4; ++i) {
        int c = tid + i * 1024;            // 0..4095 16B chunks
        *(ushort8v*)(xb0 + c * 8) = *(const ushort8v*)&lbuf[c * 8];
    }
}

// ---------------------------------------------------------------------------
// BIG-PATH GEMM: R5-exact barrier-free loop (ring-2 B, vmcnt(2); A ds_read
// ring-2, lgkmcnt(2); setprio) — but the x pack is replaced by 8 linear
// global_load_lds_dwordx4 from the pre-packed Xb (LLC-hot), retired with a
// counted vmcnt(4) that keeps B(0),B(1) in flight, then raw s_barrier.
// No pack VALU, no scattered LDS writes, no HBM-latency-exposed serial read.
// ---------------------------------------------------------------------------
__global__ __launch_bounds__(512, 2) void gemm_ait_xb(
    const float* __restrict__ x, const unsigned short* __restrict__ Xb,
    const unsigned short* __restrict__ Wb2,
    const float* __restrict__ bias, const float* __restrict__ u,
    float* __restrict__ numer, float* __restrict__ denom, int T)
{
    __shared__ __align__(128) unsigned short xa[32768];  // 64 KiB A-tile
    __shared__ float rowpart[8][64];                     // 2 KiB

    const int tid  = threadIdx.x;
    const int wave = tid >> 6;        // 0..7 : cols wave*64..+63
    const int lane = tid & 63;
    const int half = lane >> 5;
    const int nl   = lane & 31;
    const int m0   = blockIdx.x * 64;

    f32x16 acc[2][2];
    #pragma unroll
    for (int mi = 0; mi < 2; ++mi)
        #pragma unroll
        for (int ni = 0; ni < 2; ++ni)
            #pragma unroll
            for (int r = 0; r < 16; ++r) acc[mi][ni][r] = 0.f;

    short8v a[2][2], b[2][2];

    const unsigned bvoff0 = (unsigned)(((wave * 4 + half) * 32 + nl) * 16);
    const unsigned abase = ldsaddr(&xa[0]) + (unsigned)(half * 512 + nl * 16);

    // ---- DMA the pre-packed A-tile: 8 x 16B per thread, linear ----
    const unsigned short* xb0 = Xb + (size_t)blockIdx.x * 32768;
    #pragma unroll
    for (int i = 0; i < 8; ++i)
        ASYNC_CP16(xb0 + tid * 8 + i * 4096, &xa[tid * 8 + i * 4096]);

    // ---- issue B(0), B(1) (stay in flight across the staging wait) ----
    #pragma unroll
    for (int i = 0; i < 2; ++i) {
        unsigned vo = bvoff0 + (unsigned)(i * 16384);
        asm volatile("global_load_dwordx4 %0, %1, %2"
                     : "=v"(b[i][0]) : "v"(vo), "s"(Wb2) : "memory");
        asm volatile("global_load_dwordx4 %0, %1, %2 offset:1024"
                     : "=v"(b[i][1]) : "v"(vo), "s"(Wb2) : "memory");
    }

    // retire the 8 DMAs (issued first), keep the 4 B loads outstanding
    asm volatile("s_waitcnt vmcnt(4)" ::: "memory");
    __builtin_amdgcn_sched_barrier(0);
    __builtin_amdgcn_s_barrier();

    // ---- A(0) prefetch ----
    asm volatile("ds_read_b128 %0, %1" : "=v"(a[0][0]) : "v"(abase) : "memory");
    asm volatile("ds_read_b128 %0, %1 offset:1024" : "=v"(a[0][1]) : "v"(abase) : "memory");

    // ---- barrier-free main loop: 32 K-steps of 16 (R5 ring-2 schedule) ----
    #pragma unroll
    for (int s = 0; s < 32; ++s) {
        if (s < 31) { asm volatile("s_waitcnt vmcnt(2)" ::: "memory"); }
        else        { asm volatile("s_waitcnt vmcnt(0)" ::: "memory"); }
        __builtin_amdgcn_sched_barrier(0);
        if (s + 1 < 32) {
            unsigned ao = abase + (unsigned)((s + 1) * 2048);
            asm volatile("ds_read_b128 %0, %1" : "=v"(a[(s + 1) & 1][0]) : "v"(ao) : "memory");
            asm volatile("ds_read_b128 %0, %1 offset:1024" : "=v"(a[(s + 1) & 1][1]) : "v"(ao) : "memory");
            asm volatile("s_waitcnt lgkmcnt(2)" ::: "memory");
        } else {
            asm volatile("s_waitcnt lgkmcnt(0)" ::: "memory");
        }
        __builtin_amdgcn_sched_barrier(0);
        __builtin_amdgcn_s_setprio(1);
        acc[0][0] = __builtin_amdgcn_mfma_f32_32x32x16_bf16(a[s & 1][0], b[s & 1][0], acc[0][0], 0, 0, 0);
        acc[0][1] = __builtin_amdgcn_mfma_f32_32x32x16_bf16(a[s & 1][0], b[s & 1][1], acc[0][1], 0, 0, 0);
        acc[1][0] = __builtin_amdgcn_mfma_f32_32x32x16_bf16(a[s & 1][1], b[s & 1][0], acc[1][0], 0, 0, 0);
        acc[1][1] = __builtin_amdgcn_mfma_f32_32x32x16_bf16(a[s & 1][1], b[s & 1][1], acc[1][1], 0, 0, 0);
        __builtin_amdgcn_s_setprio(0);
        if (s + 2 < 32) {
            unsigned vo = bvoff0 + (unsigned)((s + 2) * 16384);
            asm volatile("global_load_dwordx4 %0, %1, %2"
                         : "=v"(b[s & 1][0]) : "v"(vo), "s"(Wb2) : "memory");
            asm volatile("global_load_dwordx4 %0, %1, %2 offset:1024"
                         : "=v"(b[s & 1][1]) : "v"(vo), "s"(Wb2) : "memory");
        }
    }

    // ---- epilogue 1: ait[m] = sum_e tanh(C[m][e]+bias[e]) * u[e] ----
    // C/D layout: col = lane&31, row = (reg&3) + 8*(reg>>2) + 4*(lane>>5)
    float rowsum[2][16];
    #pragma unroll
    for (int mi = 0; mi < 2; ++mi)
        #pragma unroll
        for (int r = 0; r < 16; ++r) rowsum[mi][r] = 0.f;

    #pragma unroll
    for (int mi = 0; mi < 2; ++mi) {
        #pragma unroll
        for (int ni = 0; ni < 2; ++ni) {
            int col = wave * 64 + ni * 32 + nl;
            float be = bias[col], ue = u[col];
            #pragma unroll
            for (int r = 0; r < 16; ++r)
                rowsum[mi][r] += fast_tanh(acc[mi][ni][r] + be) * ue;
        }
    }
    #pragma unroll
    for (int mi = 0; mi < 2; ++mi)
        #pragma unroll
        for (int r = 0; r < 16; ++r) {
            float v = rowsum[mi][r];
            v += __shfl_xor(v, 1, 64);
            v += __shfl_xor(v, 2, 64);
            v += __shfl_xor(v, 4, 64);
            v += __shfl_xor(v, 8, 64);
            v += __shfl_xor(v, 16, 64);
            rowsum[mi][r] = v;
        }
    if (nl == 0) {
        #pragma unroll
        for (int mi = 0; mi < 2; ++mi)
            #pragma unroll
            for (int r = 0; r < 16; ++r) {
                int row = mi * 32 + (r & 3) + 8 * (r >> 2) + 4 * half;
                rowpart[wave][row] = rowsum[mi][r];
            }
    }
    __syncthreads();   // rowpart complete; xa dead -> reusable as scratch

    // ---- epilogue 2: e = exp(ait), denom atomic ----
    const int bidx = m0 / T;
    float* evals = (float*)&xa[0];              // 64 floats
    if (tid < 64) {
        float s = 0.f;
        #pragma unroll
        for (int w = 0; w < 8; ++w) s += rowpart[w][tid];
        float e = __expf(s);
        evals[tid] = e;
        float t = e;
        t += __shfl_xor(t, 1, 64);
        t += __shfl_xor(t, 2, 64);
        t += __shfl_xor(t, 4, 64);
        t += __shfl_xor(t, 8, 64);
        t += __shfl_xor(t, 16, 64);
        t += __shfl_xor(t, 32, 64);
        if (tid == 0) atomicAdd(denom + bidx, t);
    }
    __syncthreads();   // evals ready

    // ---- epilogue 3: numer[b][d] += sum_r e[r] * x[m0+r][d]  (x LLC-hot) ----
    const int dg = tid >> 7;                    // 0..3
    const int d4 = (tid & 127) << 2;            // 0..508
    const float* xp = x + (size_t)m0 * D_DIM + d4;
    float4 pacc = {0.f, 0.f, 0.f, 0.f};
    #pragma unroll 4
    for (int r = dg; r < 64; r += 4) {
        float e = evals[r];
        float4 xv = *(const float4*)(xp + (size_t)r * D_DIM);
        pacc.x += e * xv.x; pacc.y += e * xv.y;
        pacc.z += e * xv.z; pacc.w += e * xv.w;
    }
    float4* ptmp = (float4*)&xa[256];
    if (dg > 0) ptmp[(dg - 1) * 128 + (tid & 127)] = pacc;
    __syncthreads();
    if (dg == 0) {
        float4 o0 = ptmp[tid], o1 = ptmp[128 + tid], o2 = ptmp[256 + tid];
        float* np = numer + (size_t)bidx * D_DIM + d4;
        atomicAdd(np + 0, pacc.x + o0.x + o1.x + o2.x);
        atomicAdd(np + 1, pacc.y + o0.y + o1.y + o2.y);
        atomicAdd(np + 2, pacc.z + o0.z + o1.z + o2.z);
        atomicAdd(np + 3, pacc.w + o0.w + o1.w + o2.w);
    }
}

// ---------------------------------------------------------------------------
// MID-PATH GEMM (R9 verbatim, passed): in-kernel pack + ring-3 B.
// Used only when ws is too small for Xb.
// ---------------------------------------------------------------------------
__global__ __launch_bounds__(512, 2) void gemm_ait_fused(
    const float* __restrict__ x, const unsigned short* __restrict__ Wb2,
    const float* __restrict__ bias, const float* __restrict__ u,
    float* __restrict__ numer, float* __restrict__ denom, int T)
{
    __shared__ __align__(128) unsigned short xa[32768];
    __shared__ float rowpart[8][64];

    const int tid  = threadIdx.x;
    const int wave = tid >> 6;
    const int lane = tid & 63;
    const int half = lane >> 5;
    const int nl   = lane & 31;
    const int m0   = blockIdx.x * 64;

    f32x16 acc[2][2];
    #pragma unroll
    for (int mi = 0; mi < 2; ++mi)
        #pragma unroll
        for (int ni = 0; ni < 2; ++ni)
            #pragma unroll
            for (int r = 0; r < 16; ++r) acc[mi][ni][r] = 0.f;

    short8v a[2][2], b[3][2];

    const unsigned bvoff0 = (unsigned)(((wave * 4 + half) * 32 + nl) * 16);
    const unsigned abase = ldsaddr(&xa[0]) + (unsigned)(half * 512 + nl * 16);

    const float* x0 = x + (size_t)m0 * D_DIM;

    #pragma unroll
    for (int i = 0; i < 3; ++i) {
        unsigned vo = bvoff0 + (unsigned)(i * 16384);
        asm volatile("global_load_dwordx4 %0, %1, %2"
                     : "=v"(b[i][0]) : "v"(vo), "s"(Wb2) : "memory");
        asm volatile("global_load_dwordx4 %0, %1, %2 offset:1024"
                     : "=v"(b[i][1]) : "v"(vo), "s"(Wb2) : "memory");
    }

    #pragma unroll
    for (int i = 0; i < 16; ++i) {
        int chunk = tid + i * 512;
        int row = chunk >> 7;
        int c4  = (chunk & 127) * 4;
        float4 v = *(const float4*)(x0 + (size_t)row * D_DIM + c4);
        pack_store(xa, row, c4, v);
    }
    __syncthreads();

    asm volatile("ds_read_b128 %0, %1" : "=v"(a[0][0]) : "v"(abase) : "memory");
    asm volatile("ds_read_b128 %0, %1 offset:1024" : "=v"(a[0][1]) : "v"(abase) : "memory");

    #pragma unroll
    for (int s = 0; s < 32; ++s) {
        if (s < 30)      { asm volatile("s_waitcnt vmcnt(4)" ::: "memory"); }
        else if (s == 30){ asm volatile("s_waitcnt vmcnt(2)" ::: "memory"); }
        else             { asm volatile("s_waitcnt vmcnt(0)" ::: "memory"); }
        __builtin_amdgcn_sched_barrier(0);
        if (s + 1 < 32) {
            unsigned ao = abase + (unsigned)((s + 1) * 2048);
            asm volatile("ds_read_b128 %0, %1" : "=v"(a[(s + 1) & 1][0]) : "v"(ao) : "memory");
            asm volatile("ds_read_b128 %0, %1 offset:1024" : "=v"(a[(s + 1) & 1][1]) : "v"(ao) : "memory");
            asm volatile("s_waitcnt lgkmcnt(2)" ::: "memory");
        } else {
            asm volatile("s_waitcnt lgkmcnt(0)" ::: "memory");
        }
        __builtin_amdgcn_sched_barrier(0);
        __builtin_amdgcn_s_setprio(1);
        acc[0][0] = __builtin_amdgcn_mfma_f32_32x32x16_bf16(a[s & 1][0], b[s % 3][0], acc[0][0], 0, 0, 0);
        acc[0][1] = __builtin_amdgcn_mfma_f32_32x32x16_bf16(a[s & 1][0], b[s % 3][1], acc[0][1], 0, 0, 0);
        acc[1][0] = __builtin_amdgcn_mfma_f32_32x32x16_bf16(a[s & 1][1], b[s % 3][0], acc[1][0], 0, 0, 0);
        acc[1][1] = __builtin_amdgcn_mfma_f32_32x32x16_bf16(a[s & 1][1], b[s % 3][1], acc[1][1], 0, 0, 0);
        __builtin_amdgcn_s_setprio(0);
        if (s + 3 < 32) {
            unsigned vo = bvoff0 + (unsigned)((s + 3) * 16384);
            asm volatile("global_load_dwordx4 %0, %1, %2"
                         : "=v"(b[s % 3][0]) : "v"(vo), "s"(Wb2) : "memory");
            asm volatile("global_load_dwordx4 %0, %1, %2 offset:1024"
                         : "=v"(b[s % 3][1]) : "v"(vo), "s"(Wb2) : "memory");
        }
    }

    float rowsum[2][16];
    #pragma unroll
    for (int mi = 0; mi < 2; ++mi)
        #pragma unroll
        for (int r = 0; r < 16; ++r) rowsum[mi][r] = 0.f;

    #pragma unroll
    for (int mi = 0; mi < 2; ++mi) {
        #pragma unroll
        for (int ni = 0; ni < 2; ++ni) {
            int col = wave * 64 + ni * 32 + nl;
            float be = bias[col], ue = u[col];
            #pragma unroll
            for (int r = 0; r < 16; ++r)
                rowsum[mi][r] += fast_tanh(acc[mi][ni][r] + be) * ue;
        }
    }
    #pragma unroll
    for (int mi = 0; mi < 2; ++mi)
        #pragma unroll
        for (int r = 0; r < 16; ++r) {
            float v = rowsum[mi][r];
            v += __shfl_xor(v, 1, 64);
            v += __shfl_xor(v, 2, 64);
            v += __shfl_xor(v, 4, 64);
            v += __shfl_xor(v, 8, 64);
            v += __shfl_xor(v, 16, 64);
            rowsum[mi][r] = v;
        }
    if (nl == 0) {
        #pragma unroll
        for (int mi = 0; mi < 2; ++mi)
            #pragma unroll
            for (int r = 0; r < 16; ++r) {
                int row = mi * 32 + (r & 3) + 8 * (r >> 2) + 4 * half;
                rowpart[wave][row] = rowsum[mi][r];
            }
    }
    __syncthreads();

    const int bidx = m0 / T;
    float* evals = (float*)&xa[0];
    if (tid < 64) {
        float s = 0.f;
        #pragma unroll
        for (int w = 0; w < 8; ++w) s += rowpart[w][tid];
        float e = __expf(s);
        evals[tid] = e;
        float t = e;
        t += __shfl_xor(t, 1, 64);
        t += __shfl_xor(t, 2, 64);
        t += __shfl_xor(t, 4, 64);
        t += __shfl_xor(t, 8, 64);
        t += __shfl_xor(t, 16, 64);
        t += __shfl_xor(t, 32, 64);
        if (tid == 0) atomicAdd(denom + bidx, t);
    }
    __syncthreads();

    const int dg = tid >> 7;
    const int d4 = (tid & 127) << 2;
    const float* xp = x + (size_t)m0 * D_DIM + d4;
    float4 pacc = {0.f, 0.f, 0.f, 0.f};
    #pragma unroll 4
    for (int r = dg; r < 64; r += 4) {
        float e = evals[r];
        float4 xv = *(const float4*)(xp + (size_t)r * D_DIM);
        pacc.x += e * xv.x; pacc.y += e * xv.y;
        pacc.z += e * xv.z; pacc.w += e * xv.w;
    }
    float4* ptmp = (float4*)&xa[256];
    if (dg > 0) ptmp[(dg - 1) * 128 + (tid & 127)] = pacc;
    __syncthreads();
    if (dg == 0) {
        float4 o0 = ptmp[tid], o1 = ptmp[128 + tid], o2 = ptmp[256 + tid];
        float* np = numer + (size_t)bidx * D_DIM + d4;
        atomicAdd(np + 0, pacc.x + o0.x + o1.x + o2.x);
        atomicAdd(np + 1, pacc.y + o0.y + o1.y + o2.y);
        atomicAdd(np + 2, pacc.z + o0.z + o1.z + o2.z);
        atomicAdd(np + 3, pacc.w + o0.w + o1.w + o2.w);
    }
}

// ---- final divide: out[b][d] = numer[b][d] / (denom[b] + eps) ----
__global__ __launch_bounds__(128) void out_div_kernel(
    const float* __restrict__ numer, const float* __restrict__ denom,
    float* __restrict__ out)
{
    const int b = blockIdx.x;
    const int tid = threadIdx.x;
    float inv = 1.0f / (denom[b] + 1e-7f);
    float4 v = *(const float4*)(numer + (size_t)b * D_DIM + tid * 4);
    v.x *= inv; v.y *= inv; v.z *= inv; v.w *= inv;
    *(float4*)(out + (size_t)b * D_DIM + tid * 4) = v;
}

// ---- fp32 fallback GEMM (only if ws < 768 KiB — never observed) ----
__global__ __launch_bounds__(256) void gemm_ait_f32(
    const float* __restrict__ x, const float* __restrict__ W,
    const float* __restrict__ bias, const float* __restrict__ u,
    float* __restrict__ ait)
{
    __shared__ float xsf[64][68];
    __shared__ float wshf[64][132];
    const int tid = threadIdx.x;
    const int tx = tid & 15, ty = tid >> 4;
    const int m0 = blockIdx.x * 64;
    float rowsum[4] = {0.f, 0.f, 0.f, 0.f};
    for (int e0 = 0; e0 < D_DIM; e0 += 128) {
        float acc[4][8];
        #pragma unroll
        for (int i = 0; i < 4; ++i)
            #pragma unroll
            for (int j = 0; j < 8; ++j) acc[i][j] = 0.f;
        for (int kc = 0; kc < D_DIM; kc += 64) {
            #pragma unroll
            for (int i = 0; i < 4; ++i) {
                int idx = tid + i * 256;
                int r = idx >> 4, c = (idx & 15) * 4;
                *(float4*)&xsf[r][c] = *(const float4*)(x + (size_t)(m0 + r) * D_DIM + kc + c);
            }
            #pragma unroll
            for (int i = 0; i < 8; ++i) {
                int idx = tid + i * 256;
                int r = idx >> 5, c = (idx & 31) * 4;
                *(float4*)&wshf[r][c] = *(const float4*)(W + (size_t)(kc + r) * D_DIM + e0 + c);
            }
            __syncthreads();
            #pragma unroll 4
            for (int k = 0; k < 64; ++k) {
                float xv[4];
                #pragma unroll
                for (int i = 0; i < 4; ++i) xv[i] = xsf[ty * 4 + i][k];
                float4 w0 = *(const float4*)&wshf[k][tx * 8];
                float4 w1 = *(const float4*)&wshf[k][tx * 8 + 4];
                #pragma unroll
                for (int i = 0; i < 4; ++i) {
                    acc[i][0] += xv[i] * w0.x; acc[i][1] += xv[i] * w0.y;
                    acc[i][2] += xv[i] * w0.z; acc[i][3] += xv[i] * w0.w;
                    acc[i][4] += xv[i] * w1.x; acc[i][5] += xv[i] * w1.y;
                    acc[i][6] += xv[i] * w1.z; acc[i][7] += xv[i] * w1.w;
                }
            }
            __syncthreads();
        }
        #pragma unroll
        for (int j = 0; j < 8; ++j) {
            int e = e0 + tx * 8 + j;
            float be = bias[e], ue = u[e];
            #pragma unroll
            for (int i = 0; i < 4; ++i) rowsum[i] += tanhf(acc[i][j] + be) * ue;
        }
    }
    float* red = &xsf[0][0];
    #pragma unroll
    for (int i = 0; i < 4; ++i) red[(ty * 4 + i) * 16 + tx] = rowsum[i];
    __syncthreads();
    if (tid < 64) {
        float s = 0.f;
        #pragma unroll
        for (int j = 0; j < 16; ++j) s += red[tid * 16 + j];
        ait[m0 + tid] = s;
    }
}

// ---- softmax over T (fallback path) ----
__global__ __launch_bounds__(256) void softmax_kernel(float* __restrict__ ait, int T)
{
    const int b = blockIdx.x;
    float* p = ait + (size_t)b * T;
    const int tid = threadIdx.x;
    float ev[8];
    float local = 0.f;
    #pragma unroll
    for (int i = 0; i < 8; ++i) {
        ev[i] = expf(p[tid + i * 256]);
        local += ev[i];
    }
    #pragma unroll
    for (int off = 32; off > 0; off >>= 1)
        local += __shfl_down(local, off, 64);
    __shared__ float wsum[4];
    const int wv = tid >> 6, lane = tid & 63;
    if (lane == 0) wsum[wv] = local;
    __syncthreads();
    float total = wsum[0] + wsum[1] + wsum[2] + wsum[3];
    float inv = 1.0f / (total + 1e-7f);
    #pragma unroll
    for (int i = 0; i < 8; ++i) p[tid + i * 256] = ev[i] * inv;
}

// ---- fallback pool (tiny-ws path only) ----
__global__ __launch_bounds__(256) void pool_atomic_kernel(
    const float* __restrict__ x, const float* __restrict__ a,
    float* __restrict__ out, int T)
{
    const int chunks = T >> 8;
    const int b = blockIdx.x / chunks;
    const int c = blockIdx.x % chunks;
    const int tid = threadIdx.x;
    const int th = tid >> 7;
    const int d = (tid & 127) * 4;
    const float* xp = x + ((size_t)b * T + c * 256) * D_DIM + d;
    const float* ap = a + (size_t)b * T + c * 256;
    float4 acc = {0.f, 0.f, 0.f, 0.f};
    #pragma unroll 8
    for (int t = th; t < 256; t += 2) {
        float s = ap[t];
        float4 xv = *(const float4*)(xp + (size_t)t * D_DIM);
        acc.x += xv.x * s; acc.y += xv.y * s;
        acc.z += xv.z * s; acc.w += xv.w * s;
    }
    __shared__ float4 tmp[128];
    if (th == 1) tmp[tid & 127] = acc;
    __syncthreads();
    if (th == 0) {
        float4 o = tmp[tid];
        float* op = out + (size_t)b * D_DIM + tid * 4;
        atomicAdd(op + 0, acc.x + o.x);
        atomicAdd(op + 1, acc.y + o.y);
        atomicAdd(op + 2, acc.z + o.z);
        atomicAdd(op + 3, acc.w + o.w);
    }
}

extern "C" void kernel_launch(void* const* d_in, const int* in_sizes, int n_in,
                              void* d_out, int out_size, void* d_ws, size_t ws_size,
                              hipStream_t stream)
{
    const float* x    = (const float*)d_in[0];
    const float* W    = (const float*)d_in[1];
    const float* bias = (const float*)d_in[2];
    const float* u    = (const float*)d_in[3];
    float* out = (float*)d_out;

    const int Dd = in_sizes[2];          // 512
    const int M  = in_sizes[0] / Dd;     // 65536
    const int B  = out_size / Dd;        // 32
    const int T  = M / B;                // 2048
    const int chunks = T >> 8;           // 8

    const size_t wb_bytes  = (size_t)Dd * Dd * sizeof(unsigned short);   // 512 KiB
    const size_t ait_bytes = (size_t)M * sizeof(float);                  // 256 KiB
    const size_t xb_off    = 1u << 20;                                   // 1 MiB
    const size_t xb_bytes  = (size_t)M * Dd * sizeof(unsigned short);    // 64 MiB

    if (ws_size >= xb_off + xb_bytes) {
        // [0,512K): Wb2. [512K,576K+128): numer+denom. [1M, 1M+64M): Xb.
        unsigned short* Wb2 = (unsigned short*)d_ws;
        float* numer = (float*)((char*)d_ws + wb_bytes);
        float* denom = numer + (size_t)B * Dd;
        unsigned short* Xb = (unsigned short*)((char*)d_ws + xb_off);
        const int zero_count = B * Dd + B;

        prep_kernel<<<dim3(16 + M / 64), dim3(1024), 0, stream>>>(
            W, Wb2, x, Xb, numer, zero_count);
        gemm_ait_xb<<<dim3(M / 64), dim3(512), 0, stream>>>(
            x, Xb, Wb2, bias, u, numer, denom, T);
        out_div_kernel<<<dim3(B), dim3(128), 0, stream>>>(numer, denom, out);
    } else if (ws_size >= wb_bytes + ait_bytes) {
        unsigned short* Wb2 = (unsigned short*)d_ws;
        float* numer = (float*)((char*)d_ws + wb_bytes);
        float* denom = numer + (size_t)B * Dd;
        const int zero_count = B * Dd + B;

        wt_kernel<<<dim3(16), dim3(1024), 0, stream>>>(W, Wb2, numer, zero_count);
        gemm_ait_fused<<<dim3(M / 64), dim3(512), 0, stream>>>(x, Wb2, bias, u,
                                                               numer, denom, T);
        out_div_kernel<<<dim3(B), dim3(128), 0, stream>>>(numer, denom, out);
    } else {
        float* ait = (float*)d_ws;
        gemm_ait_f32<<<dim3(M / 64), dim3(256), 0, stream>>>(x, W, bias, u, ait);
        softmax_kernel<<<dim3(B), dim3(256), 0, stream>>>(ait, T);
        hipMemsetAsync(d_out, 0, (size_t)out_size * sizeof(float), stream);
        pool_atomic_kernel<<<dim3(B * chunks), dim3(256), 0, stream>>>(x, ait, out, T);
    }
}

// Round 11
// 235.112 us; speedup vs baseline: 1.1601x; 1.1601x over previous
//
#include <hip/hip_runtime.h>
#include <math.h>

#define D_DIM 512

typedef short short8v __attribute__((ext_vector_type(8)));
typedef unsigned short ushort8v __attribute__((ext_vector_type(8)));
typedef unsigned short ushort4v __attribute__((ext_vector_type(4)));
typedef float f32x16 __attribute__((ext_vector_type(16)));

__device__ inline unsigned short f2bf(float f) {
    union { float f; unsigned int u; } a; a.f = f;
    unsigned int u = a.u;
    unsigned int r = (u + 0x7fffu + ((u >> 16) & 1u)) >> 16;  // RNE
    return (unsigned short)r;
}

// fast tanh: 1 - 2/(e^{2y}+1); saturates correctly at +-1
__device__ inline float fast_tanh(float y) {
    float e2 = __expf(2.f * y);
    return 1.f - __fdividef(2.f, e2 + 1.f);
}

// 32-bit LDS offset for inline-asm DS ops
__device__ inline unsigned ldsaddr(const void* p) {
    return (unsigned)(size_t)(__attribute__((address_space(3))) const void*)p;
}

// ---------------------------------------------------------------------------
// wt: W[k][e] fp32 -> Wb2 bf16, 32 blocks = one 16-k stage each (widened from
// 16 stage-pair blocks; same verified layout, 2x parallelism, half traffic
// per block).  Wb2 ushort idx: s16*8192 + ((g*2+half)*32+nl)*8 + j
//   holding W[k = s16*16 + half*8 + j][e = g*32 + nl],  g=e>>5, nl=e&31.
// Block 0 additionally zeroes the numer/denom accumulators.
// ---------------------------------------------------------------------------
__global__ __launch_bounds__(1024) void wt_kernel(const float* __restrict__ W,
                                                  unsigned short* __restrict__ Wb2,
                                                  float* __restrict__ zero_base,
                                                  int zero_count) {
    __shared__ __align__(16) unsigned short lbuf[8192];    // 16 KiB = 1 stage
    const int s = blockIdx.x;          // 0..31 (16-k stage)
    const int tid = threadIdx.x;
    if (s == 0) {
        for (int i = tid; i < zero_count; i += 1024) zero_base[i] = 0.f;
    }
    #pragma unroll
    for (int i = 0; i < 2; ++i) {
        int flat = tid + i * 1024;     // 0..2047 float4-chunks of this stage
        int kr = flat >> 7;            // 0..15
        int e4 = (flat & 127) * 4;
        float4 v = *(const float4*)(W + (size_t)(s * 16 + kr) * D_DIM + e4);
        int half = (kr >> 3) & 1, j = kr & 7;
        float vv[4] = {v.x, v.y, v.z, v.w};
        #pragma unroll
        for (int q = 0; q < 4; ++q) {
            int e = e4 + q, g = e >> 5, nl = e & 31;
            lbuf[((g * 2 + half) * 32 + nl) * 8 + j] = f2bf(vv[q]);
        }
    }
    __syncthreads();
    // 1024 8-ushort chunks, linear coalesced store
    *(ushort8v*)(Wb2 + (size_t)s * 8192 + tid * 8) = *(const ushort8v*)&lbuf[tid * 8];
}

// ---------------------------------------------------------------------------
// A-tile pack store (R5-verified linear layout, scalar f2bf).
// element x[row][k] -> xa[(((ks*2+mi)*2+hf)*32 + r5)*8 + j],
//   ks=k>>4, hf=(k>>3)&1, j=k&7, mi=row>>5, r5=row&31.
// ---------------------------------------------------------------------------
__device__ __forceinline__ void pack_store(unsigned short* xa, int row, int c4, float4 v) {
    int ks = c4 >> 4, hf = (c4 >> 3) & 1, j0 = c4 & 7;
    int mi = row >> 5, r5 = row & 31;
    ushort4v pk;
    pk[0] = f2bf(v.x); pk[1] = f2bf(v.y); pk[2] = f2bf(v.z); pk[3] = f2bf(v.w);
    *(ushort4v*)&xa[(((ks * 2 + mi) * 2 + hf) * 32 + r5) * 8 + j0] = pk;
}

// ---------------------------------------------------------------------------
// Fused MFMA GEMM + tanh/dot-u + exp + weighted-pool epilogue.
// R9 VERBATIM (239.96 us total, gemm 101 us, best verified): one 64-row
// tile/block, grid M/64, barrier-free K-loop (32 stages of 16), A ds_read
// ring-2 w/ lgkmcnt(2), B global->reg RING-3 w/ vmcnt(4), setprio around
// MFMAs, full pack before the loop.  VGPR ~56 -> 2 blocks/CU.
// Counting: prologue issues B(0),B(1),B(2).  Stage s: {B(s),B(s+1),B(s+2)}
// outstanding (6 ops); vmcnt(4) -> B(s) ready; MFMA on b[s%3]; issue B(s+3)
// into that slot.  Tail: s=29 vmcnt(4), s=30 vmcnt(2), s=31 vmcnt(0).
// ---------------------------------------------------------------------------
__global__ __launch_bounds__(512, 2) void gemm_ait_fused(
    const float* __restrict__ x, const unsigned short* __restrict__ Wb2,
    const float* __restrict__ bias, const float* __restrict__ u,
    float* __restrict__ numer, float* __restrict__ denom, int T)
{
    __shared__ __align__(128) unsigned short xa[32768];  // 64 KiB A-tile
    __shared__ float rowpart[8][64];                     // 2 KiB

    const int tid  = threadIdx.x;
    const int wave = tid >> 6;        // 0..7 : cols wave*64..+63
    const int lane = tid & 63;
    const int half = lane >> 5;
    const int nl   = lane & 31;
    const int m0   = blockIdx.x * 64;

    f32x16 acc[2][2];
    #pragma unroll
    for (int mi = 0; mi < 2; ++mi)
        #pragma unroll
        for (int ni = 0; ni < 2; ++ni)
            #pragma unroll
            for (int r = 0; r < 16; ++r) acc[mi][ni][r] = 0.f;

    short8v a[2][2], b[3][2];

    // per-lane byte offset of this wave's B-fragment (ni=0) within a stage
    const unsigned bvoff0 = (unsigned)(((wave * 4 + half) * 32 + nl) * 16);
    // A read base (linear): per-stage address = abase + s*2048 (+1024 for mi=1)
    const unsigned abase = ldsaddr(&xa[0]) + (unsigned)(half * 512 + nl * 16);

    const float* x0 = x + (size_t)m0 * D_DIM;

    // ---- issue B(0), B(1), B(2) early (L2 warm-up overlaps the x pack) ----
    #pragma unroll
    for (int i = 0; i < 3; ++i) {
        unsigned vo = bvoff0 + (unsigned)(i * 16384);
        asm volatile("global_load_dwordx4 %0, %1, %2"
                     : "=v"(b[i][0]) : "v"(vo), "s"(Wb2) : "memory");
        asm volatile("global_load_dwordx4 %0, %1, %2 offset:1024"
                     : "=v"(b[i][1]) : "v"(vo), "s"(Wb2) : "memory");
    }

    // ---- pack x tile into xa (R5-verified) ----
    #pragma unroll
    for (int i = 0; i < 16; ++i) {
        int chunk = tid + i * 512;             // 0..8191 float4-chunks
        int row = chunk >> 7;                  // 0..63
        int c4  = (chunk & 127) * 4;           // 0..508, coalesced across tid
        float4 v = *(const float4*)(x0 + (size_t)row * D_DIM + c4);
        pack_store(xa, row, c4, v);
    }
    __syncthreads();   // the ONLY barrier before the epilogue

    // ---- A(0) prefetch ----
    asm volatile("ds_read_b128 %0, %1" : "=v"(a[0][0]) : "v"(abase) : "memory");
    asm volatile("ds_read_b128 %0, %1 offset:1024" : "=v"(a[0][1]) : "v"(abase) : "memory");

    // ---- barrier-free main loop: 32 K-steps of 16, B ring-3 ----
    #pragma unroll
    for (int s = 0; s < 32; ++s) {
        // retire the B(s) pair; keep up to B(s+1),B(s+2) in flight
        if (s < 30)      { asm volatile("s_waitcnt vmcnt(4)" ::: "memory"); }
        else if (s == 30){ asm volatile("s_waitcnt vmcnt(2)" ::: "memory"); }
        else             { asm volatile("s_waitcnt vmcnt(0)" ::: "memory"); }
        __builtin_amdgcn_sched_barrier(0);
        // A(s+1) prefetch, then A(s) ready
        if (s + 1 < 32) {
            unsigned ao = abase + (unsigned)((s + 1) * 2048);
            asm volatile("ds_read_b128 %0, %1" : "=v"(a[(s + 1) & 1][0]) : "v"(ao) : "memory");
            asm volatile("ds_read_b128 %0, %1 offset:1024" : "=v"(a[(s + 1) & 1][1]) : "v"(ao) : "memory");
            asm volatile("s_waitcnt lgkmcnt(2)" ::: "memory");
        } else {
            asm volatile("s_waitcnt lgkmcnt(0)" ::: "memory");
        }
        __builtin_amdgcn_sched_barrier(0);
        __builtin_amdgcn_s_setprio(1);
        acc[0][0] = __builtin_amdgcn_mfma_f32_32x32x16_bf16(a[s & 1][0], b[s % 3][0], acc[0][0], 0, 0, 0);
        acc[0][1] = __builtin_amdgcn_mfma_f32_32x32x16_bf16(a[s & 1][0], b[s % 3][1], acc[0][1], 0, 0, 0);
        acc[1][0] = __builtin_amdgcn_mfma_f32_32x32x16_bf16(a[s & 1][1], b[s % 3][0], acc[1][0], 0, 0, 0);
        acc[1][1] = __builtin_amdgcn_mfma_f32_32x32x16_bf16(a[s & 1][1], b[s % 3][1], acc[1][1], 0, 0, 0);
        __builtin_amdgcn_s_setprio(0);
        // issue B(s+3) into the slot the MFMAs above just consumed
        if (s + 3 < 32) {
            unsigned vo = bvoff0 + (unsigned)((s + 3) * 16384);
            asm volatile("global_load_dwordx4 %0, %1, %2"
                         : "=v"(b[s % 3][0]) : "v"(vo), "s"(Wb2) : "memory");
            asm volatile("global_load_dwordx4 %0, %1, %2 offset:1024"
                         : "=v"(b[s % 3][1]) : "v"(vo), "s"(Wb2) : "memory");
        }
    }

    // ---- epilogue 1: ait[m] = sum_e tanh(C[m][e]+bias[e]) * u[e] ----
    // C/D layout: col = lane&31, row = (reg&3) + 8*(reg>>2) + 4*(lane>>5)
    float rowsum[2][16];
    #pragma unroll
    for (int mi = 0; mi < 2; ++mi)
        #pragma unroll
        for (int r = 0; r < 16; ++r) rowsum[mi][r] = 0.f;

    #pragma unroll
    for (int mi = 0; mi < 2; ++mi) {
        #pragma unroll
        for (int ni = 0; ni < 2; ++ni) {
            int col = wave * 64 + ni * 32 + nl;
            float be = bias[col], ue = u[col];
            #pragma unroll
            for (int r = 0; r < 16; ++r)
                rowsum[mi][r] += fast_tanh(acc[mi][ni][r] + be) * ue;
        }
    }
    #pragma unroll
    for (int mi = 0; mi < 2; ++mi)
        #pragma unroll
        for (int r = 0; r < 16; ++r) {
            float v = rowsum[mi][r];
            v += __shfl_xor(v, 1, 64);
            v += __shfl_xor(v, 2, 64);
            v += __shfl_xor(v, 4, 64);
            v += __shfl_xor(v, 8, 64);
            v += __shfl_xor(v, 16, 64);
            rowsum[mi][r] = v;
        }
    if (nl == 0) {
        #pragma unroll
        for (int mi = 0; mi < 2; ++mi)
            #pragma unroll
            for (int r = 0; r < 16; ++r) {
                int row = mi * 32 + (r & 3) + 8 * (r >> 2) + 4 * half;
                rowpart[wave][row] = rowsum[mi][r];
            }
    }
    __syncthreads();   // rowpart complete; xa dead -> reusable as scratch

    // ---- epilogue 2: e = exp(ait), denom atomic ----
    const int bidx = m0 / T;                    // batch of this 64-row tile
    float* evals = (float*)&xa[0];              // 64 floats (bytes 0..255)
    if (tid < 64) {
        float s = 0.f;
        #pragma unroll
        for (int w = 0; w < 8; ++w) s += rowpart[w][tid];
        float e = __expf(s);
        evals[tid] = e;
        float t = e;
        t += __shfl_xor(t, 1, 64);
        t += __shfl_xor(t, 2, 64);
        t += __shfl_xor(t, 4, 64);
        t += __shfl_xor(t, 8, 64);
        t += __shfl_xor(t, 16, 64);
        t += __shfl_xor(t, 32, 64);
        if (tid == 0) atomicAdd(denom + bidx, t);
    }
    __syncthreads();   // evals ready

    // ---- epilogue 3: numer[b][d] += sum_r e[r] * x[m0+r][d]  (x L3-hot) ----
    const int dg = tid >> 7;                    // 0..3
    const int d4 = (tid & 127) << 2;            // 0..508
    const float* xp = x + (size_t)m0 * D_DIM + d4;
    float4 pacc = {0.f, 0.f, 0.f, 0.f};
    #pragma unroll 4
    for (int r = dg; r < 64; r += 4) {
        float e = evals[r];
        float4 xv = *(const float4*)(xp + (size_t)r * D_DIM);
        pacc.x += e * xv.x; pacc.y += e * xv.y;
        pacc.z += e * xv.z; pacc.w += e * xv.w;
    }
    float4* ptmp = (float4*)&xa[256];           // bytes 512..6655, past evals
    if (dg > 0) ptmp[(dg - 1) * 128 + (tid & 127)] = pacc;
    __syncthreads();
    if (dg == 0) {
        float4 o0 = ptmp[tid], o1 = ptmp[128 + tid], o2 = ptmp[256 + tid];
        float* np = numer + (size_t)bidx * D_DIM + d4;
        atomicAdd(np + 0, pacc.x + o0.x + o1.x + o2.x);
        atomicAdd(np + 1, pacc.y + o0.y + o1.y + o2.y);
        atomicAdd(np + 2, pacc.z + o0.z + o1.z + o2.z);
        atomicAdd(np + 3, pacc.w + o0.w + o1.w + o2.w);
    }
}

// ---- final divide: out[b][d] = numer[b][d] / (denom[b] + eps) ----
__global__ __launch_bounds__(128) void out_div_kernel(
    const float* __restrict__ numer, const float* __restrict__ denom,
    float* __restrict__ out)
{
    const int b = blockIdx.x;
    const int tid = threadIdx.x;
    float inv = 1.0f / (denom[b] + 1e-7f);
    float4 v = *(const float4*)(numer + (size_t)b * D_DIM + tid * 4);
    v.x *= inv; v.y *= inv; v.z *= inv; v.w *= inv;
    *(float4*)(out + (size_t)b * D_DIM + tid * 4) = v;
}

// ---- fp32 fallback GEMM (only if ws < 768 KiB — never observed) ----
__global__ __launch_bounds__(256) void gemm_ait_f32(
    const float* __restrict__ x, const float* __restrict__ W,
    const float* __restrict__ bias, const float* __restrict__ u,
    float* __restrict__ ait)
{
    __shared__ float xsf[64][68];
    __shared__ float wshf[64][132];
    const int tid = threadIdx.x;
    const int tx = tid & 15, ty = tid >> 4;
    const int m0 = blockIdx.x * 64;
    float rowsum[4] = {0.f, 0.f, 0.f, 0.f};
    for (int e0 = 0; e0 < D_DIM; e0 += 128) {
        float acc[4][8];
        #pragma unroll
        for (int i = 0; i < 4; ++i)
            #pragma unroll
            for (int j = 0; j < 8; ++j) acc[i][j] = 0.f;
        for (int kc = 0; kc < D_DIM; kc += 64) {
            #pragma unroll
            for (int i = 0; i < 4; ++i) {
                int idx = tid + i * 256;
                int r = idx >> 4, c = (idx & 15) * 4;
                *(float4*)&xsf[r][c] = *(const float4*)(x + (size_t)(m0 + r) * D_DIM + kc + c);
            }
            #pragma unroll
            for (int i = 0; i < 8; ++i) {
                int idx = tid + i * 256;
                int r = idx >> 5, c = (idx & 31) * 4;
                *(float4*)&wshf[r][c] = *(const float4*)(W + (size_t)(kc + r) * D_DIM + e0 + c);
            }
            __syncthreads();
            #pragma unroll 4
            for (int k = 0; k < 64; ++k) {
                float xv[4];
                #pragma unroll
                for (int i = 0; i < 4; ++i) xv[i] = xsf[ty * 4 + i][k];
                float4 w0 = *(const float4*)&wshf[k][tx * 8];
                float4 w1 = *(const float4*)&wshf[k][tx * 8 + 4];
                #pragma unroll
                for (int i = 0; i < 4; ++i) {
                    acc[i][0] += xv[i] * w0.x; acc[i][1] += xv[i] * w0.y;
                    acc[i][2] += xv[i] * w0.z; acc[i][3] += xv[i] * w0.w;
                    acc[i][4] += xv[i] * w1.x; acc[i][5] += xv[i] * w1.y;
                    acc[i][6] += xv[i] * w1.z; acc[i][7] += xv[i] * w1.w;
                }
            }
            __syncthreads();
        }
        #pragma unroll
        for (int j = 0; j < 8; ++j) {
            int e = e0 + tx * 8 + j;
            float be = bias[e], ue = u[e];
            #pragma unroll
            for (int i = 0; i < 4; ++i) rowsum[i] += tanhf(acc[i][j] + be) * ue;
        }
    }
    float* red = &xsf[0][0];
    #pragma unroll
    for (int i = 0; i < 4; ++i) red[(ty * 4 + i) * 16 + tx] = rowsum[i];
    __syncthreads();
    if (tid < 64) {
        float s = 0.f;
        #pragma unroll
        for (int j = 0; j < 16; ++j) s += red[tid * 16 + j];
        ait[m0 + tid] = s;
    }
}

// ---- softmax over T (fallback path) ----
__global__ __launch_bounds__(256) void softmax_kernel(float* __restrict__ ait, int T)
{
    const int b = blockIdx.x;
    float* p = ait + (size_t)b * T;
    const int tid = threadIdx.x;
    float ev[8];
    float local = 0.f;
    #pragma unroll
    for (int i = 0; i < 8; ++i) {
        ev[i] = expf(p[tid + i * 256]);
        local += ev[i];
    }
    #pragma unroll
    for (int off = 32; off > 0; off >>= 1)
        local += __shfl_down(local, off, 64);
    __shared__ float wsum[4];
    const int wv = tid >> 6, lane = tid & 63;
    if (lane == 0) wsum[wv] = local;
    __syncthreads();
    float total = wsum[0] + wsum[1] + wsum[2] + wsum[3];
    float inv = 1.0f / (total + 1e-7f);
    #pragma unroll
    for (int i = 0; i < 8; ++i) p[tid + i * 256] = ev[i] * inv;
}

// ---- fallback pool (tiny-ws path only) ----
__global__ __launch_bounds__(256) void pool_atomic_kernel(
    const float* __restrict__ x, const float* __restrict__ a,
    float* __restrict__ out, int T)
{
    const int chunks = T >> 8;
    const int b = blockIdx.x / chunks;
    const int c = blockIdx.x % chunks;
    const int tid = threadIdx.x;
    const int th = tid >> 7;
    const int d = (tid & 127) * 4;
    const float* xp = x + ((size_t)b * T + c * 256) * D_DIM + d;
    const float* ap = a + (size_t)b * T + c * 256;
    float4 acc = {0.f, 0.f, 0.f, 0.f};
    #pragma unroll 8
    for (int t = th; t < 256; t += 2) {
        float s = ap[t];
        float4 xv = *(const float4*)(xp + (size_t)t * D_DIM);
        acc.x += xv.x * s; acc.y += xv.y * s;
        acc.z += xv.z * s; acc.w += xv.w * s;
    }
    __shared__ float4 tmp[128];
    if (th == 1) tmp[tid & 127] = acc;
    __syncthreads();
    if (th == 0) {
        float4 o = tmp[tid];
        float* op = out + (size_t)b * D_DIM + tid * 4;
        atomicAdd(op + 0, acc.x + o.x);
        atomicAdd(op + 1, acc.y + o.y);
        atomicAdd(op + 2, acc.z + o.z);
        atomicAdd(op + 3, acc.w + o.w);
    }
}

extern "C" void kernel_launch(void* const* d_in, const int* in_sizes, int n_in,
                              void* d_out, int out_size, void* d_ws, size_t ws_size,
                              hipStream_t stream)
{
    const float* x    = (const float*)d_in[0];
    const float* W    = (const float*)d_in[1];
    const float* bias = (const float*)d_in[2];
    const float* u    = (const float*)d_in[3];
    float* out = (float*)d_out;

    const int Dd = in_sizes[2];          // 512
    const int M  = in_sizes[0] / Dd;     // 65536
    const int B  = out_size / Dd;        // 32
    const int T  = M / B;                // 2048
    const int chunks = T >> 8;           // 8

    const size_t wb_bytes  = (size_t)Dd * Dd * sizeof(unsigned short);   // 512 KiB
    const size_t ait_bytes = (size_t)M * sizeof(float);                  // 256 KiB

    if (ws_size >= wb_bytes + ait_bytes) {
        // [0, 512K): Wb2.  [512K, 576K): numer (B x D).  [576K, +128B): denom.
        unsigned short* Wb2 = (unsigned short*)d_ws;
        float* numer = (float*)((char*)d_ws + wb_bytes);
        float* denom = numer + (size_t)B * Dd;
        const int zero_count = B * Dd + B;   // numer + denom contiguous

        wt_kernel<<<dim3(32), dim3(1024), 0, stream>>>(W, Wb2, numer, zero_count);
        gemm_ait_fused<<<dim3(M / 64), dim3(512), 0, stream>>>(x, Wb2, bias, u,
                                                               numer, denom, T);
        out_div_kernel<<<dim3(B), dim3(128), 0, stream>>>(numer, denom, out);
    } else {
        float* ait = (float*)d_ws;
        gemm_ait_f32<<<dim3(M / 64), dim3(256), 0, stream>>>(x, W, bias, u, ait);
        softmax_kernel<<<dim3(B), dim3(256), 0, stream>>>(ait, T);
        hipMemsetAsync(d_out, 0, (size_t)out_size * sizeof(float), stream);
        pool_atomic_kernel<<<dim3(B * chunks), dim3(256), 0, stream>>>(x, ait, out, T);
    }
}